// Round 2
// baseline (332.068 us; speedup 1.0000x reference)
//
#include <hip/hip_runtime.h>
#include <hip/hip_bf16.h>

// Problem constants
#define CIN   64
#define HH    56
#define WW    56
#define FOUT  128
#define NN    32
#define SW    4
#define WB    14          // W / SW
#define KK    3
#define PDIM  (CIN*KK*KK) // 576

// ---------------- fake-quant: absmax reduce ----------------
__global__ void absmax_kernel(const float* __restrict__ w,
                              unsigned* __restrict__ res, int nelem) {
    int i = blockIdx.x * blockDim.x + threadIdx.x;
    int stride = gridDim.x * blockDim.x;
    float m = 0.f;
    for (int idx = i; idx < nelem; idx += stride)
        m = fmaxf(m, fabsf(w[idx]));
    // wave-64 reduce
    #pragma unroll
    for (int off = 32; off > 0; off >>= 1)
        m = fmaxf(m, __shfl_down(m, off, 64));
    if ((threadIdx.x & 63) == 0)
        atomicMax(res, __float_as_uint(m));   // abs floats: uint order == float order
}

// ---------------- fake-quant: apply ----------------
__global__ void quant_kernel(const float* __restrict__ w,
                             const unsigned* __restrict__ maxbits,
                             float* __restrict__ qw, int nelem) {
    float scale = __uint_as_float(*maxbits) / 7.0f;
    int i = blockIdx.x * blockDim.x + threadIdx.x;
    if (i < nelem) {
        // matches jnp.round: round-half-to-even via rintf (default RN mode)
        qw[i] = rintf(w[i] / scale) * scale;
    }
}

// ---------------- direct conv, one block per (stripe b, h, n) ----------------
// block = 128 threads = 2 waves; thread t owns output feature f = t,
// accumulating all 14 stripe columns in registers.
__global__ __launch_bounds__(128)
void conv_kernel(const float* __restrict__ in,    // [N][C][H][W]
                 const float* __restrict__ qw,    // [SW][P][F] quantized
                 const float* __restrict__ bias,  // [F]
                 float* __restrict__ out) {       // [N][F][H][W]
    const int b = blockIdx.x;   // stripe 0..3
    const int h = blockIdx.y;   // 0..55
    const int n = blockIdx.z;   // 0..31
    const int f = threadIdx.x;  // 0..127

    __shared__ float s_in[CIN][KK][16];   // 12 KiB: 64 ch x 3 rows x 16 cols

    // cooperative staging: 3072 elements, zero-padded at true image borders
    const int w0 = b * WB - 1;
    for (int e = f; e < CIN * KK * 16; e += 128) {
        int col = e & 15;
        int r   = (e >> 4) % KK;
        int c   = e / (KK * 16);
        int hi  = h - 1 + r;
        int wi  = w0 + col;
        float v = 0.f;
        if (hi >= 0 && hi < HH && wi >= 0 && wi < WW)
            v = in[((n * CIN + c) * HH + hi) * WW + wi];
        s_in[c][r][col] = v;
    }
    __syncthreads();

    float acc[WB];
    #pragma unroll
    for (int w = 0; w < WB; ++w) acc[w] = 0.f;

    // weights for this stripe, laid out [p][f]; lane-coalesced over f
    const float* wp = qw + (size_t)b * PDIM * FOUT + f;

    for (int c = 0; c < CIN; ++c) {
        #pragma unroll
        for (int kh = 0; kh < KK; ++kh) {
            // aligned float4 broadcast reads of the 16-col row
            float4 r0 = *(const float4*)&s_in[c][kh][0];
            float4 r1 = *(const float4*)&s_in[c][kh][4];
            float4 r2 = *(const float4*)&s_in[c][kh][8];
            float4 r3 = *(const float4*)&s_in[c][kh][12];
            float row[16] = { r0.x, r0.y, r0.z, r0.w,
                              r1.x, r1.y, r1.z, r1.w,
                              r2.x, r2.y, r2.z, r2.w,
                              r3.x, r3.y, r3.z, r3.w };
            #pragma unroll
            for (int kw = 0; kw < KK; ++kw) {
                float wt = wp[(c * 9 + kh * 3 + kw) * FOUT];
                #pragma unroll
                for (int w = 0; w < WB; ++w)
                    acc[w] = fmaf(row[w + kw], wt, acc[w]);
            }
        }
    }

    const float bv = bias[f];
    float* op = out + (((size_t)n * FOUT + f) * HH + h) * WW + b * WB;
    #pragma unroll
    for (int w = 0; w < WB; ++w) op[w] = acc[w] + bv;
}

extern "C" void kernel_launch(void* const* d_in, const int* in_sizes, int n_in,
                              void* d_out, int out_size, void* d_ws, size_t ws_size,
                              hipStream_t stream) {
    const float* inputs = (const float*)d_in[0];   // [32][64][56][56]
    const float* kernel = (const float*)d_in[1];   // [1][4][576][128]
    const float* bias   = (const float*)d_in[2];   // [128]
    float* out          = (float*)d_out;           // [32][128][56][56]

    const int nelem = SW * PDIM * FOUT;            // 294912 weights

    // workspace layout: [0..3] absmax bits; 64B-aligned quantized weights after
    unsigned* ws_max = (unsigned*)d_ws;
    float*    ws_qw  = (float*)((char*)d_ws + 64);

    hipMemsetAsync(ws_max, 0, 4, stream);

    absmax_kernel<<<256, 256, 0, stream>>>(kernel, ws_max, nelem);
    quant_kernel<<<(nelem + 255) / 256, 256, 0, stream>>>(kernel, ws_max, ws_qw, nelem);

    dim3 grid(SW, HH, NN);   // (4, 56, 32) = 7168 blocks
    conv_kernel<<<grid, 128, 0, stream>>>(inputs, ws_qw, bias, out);
}

// Round 3
// 150.721 us; speedup vs baseline: 2.2032x; 2.2032x over previous
//
#include <hip/hip_runtime.h>
#include <hip/hip_bf16.h>

#define CIN   64
#define HH_   56
#define WW_   56
#define FOUT  128
#define NN    32
#define SW    4
#define WB    14
#define HG    8           // output rows per block
#define NHG   (HH_/HG)    // 7

typedef __attribute__((ext_vector_type(8))) short bf16x8;
typedef __attribute__((ext_vector_type(4))) float f32x4;

__device__ inline unsigned short f2bf(float x) {
    unsigned u = __float_as_uint(x);
    return (unsigned short)((u + 0x7FFFu + ((u >> 16) & 1u)) >> 16);  // RNE
}

// ---------------- fake-quant: absmax reduce ----------------
__global__ void absmax_kernel(const float* __restrict__ w,
                              unsigned* __restrict__ res, int nelem) {
    int i = blockIdx.x * blockDim.x + threadIdx.x;
    int stride = gridDim.x * blockDim.x;
    float m = 0.f;
    for (int idx = i; idx < nelem; idx += stride)
        m = fmaxf(m, fabsf(w[idx]));
    #pragma unroll
    for (int off = 32; off > 0; off >>= 1)
        m = fmaxf(m, __shfl_down(m, off, 64));
    if ((threadIdx.x & 63) == 0)
        atomicMax(res, __float_as_uint(m));
}

// ------- fake-quant + reorder to [b][tap][f][c] bf16 (k-order = kh,kw,c) -------
__global__ void quant_t_kernel(const float* __restrict__ w,
                               const unsigned* __restrict__ maxbits,
                               unsigned short* __restrict__ qwt) {
    float scale = __uint_as_float(*maxbits) / 7.0f;
    int o = blockIdx.x * 256 + threadIdx.x;
    if (o >= SW * 9 * FOUT * CIN) return;
    int c  = o & 63;
    int f  = (o >> 6) & 127;
    int bt = o >> 13;          // b*9 + t
    int t  = bt - (bt / 9) * 9;
    int b  = bt / 9;
    // input p-index = c*9 + t  (t = kh*3+kw)
    float v = w[((b * CIN + c) * 9 + t) * FOUT + f];
    float qv = rintf(v / scale) * scale;
    qwt[o] = f2bf(qv);
}

// ---------------- MFMA implicit-GEMM conv ----------------
// block: (hg, n, b). D[f=128][pix=112] = sum_k W^T[f][k] * patches[k][pix]
// wave w owns f-tiles {2w, 2w+1} x all 7 pixel-tiles.
__global__ __launch_bounds__(256)
void conv_mfma(const float* __restrict__ in,          // [N][C][H][W] f32
               const unsigned short* __restrict__ qwt,// [SW][9][F][C] bf16
               const float* __restrict__ bias,
               float* __restrict__ out) {             // [N][F][H][W] f32
    const int hg = blockIdx.x, n = blockIdx.y, b = blockIdx.z;
    const int h0 = hg * HG, w0 = b * WB;
    const int tid  = threadIdx.x;
    const int wave = tid >> 6, lane = tid & 63;
    const int q = lane >> 4, lm = lane & 15;

    // slab[pix = hh*16+col][c] bf16, XOR-swizzled in c to kill the 128B-stride conflict
    __shared__ __align__(16) unsigned short s_slab[160 * 64];   // 20.0 KiB
    // weights for one tap: [f][64k + 8 pad]
    __shared__ __align__(16) unsigned short s_w[128 * 72];      // 18.0 KiB

    // ---- stage input slab: rows h0-1..h0+8, cols w0-1..w0+14, f32 -> bf16, transposed ----
    for (int e = tid; e < 10 * CIN * 16; e += 256) {
        int col = e & 15;
        int c   = (e >> 4) & 63;
        int hh  = e >> 10;
        int hi  = h0 - 1 + hh;
        int wi  = w0 - 1 + col;
        float v = 0.f;
        if (hi >= 0 && hi < HH_ && wi >= 0 && wi < WW_)
            v = in[((n * CIN + c) * HH_ + hi) * WW_ + wi];
        int pix = hh * 16 + col;
        s_slab[pix * 64 + (c ^ ((pix & 7) << 3))] = f2bf(v);
    }

    // per-lane pixel coords for the 7 pixel-tiles (slab pixel-slot base ph*16+pw)
    int spb[7];
    #pragma unroll
    for (int nt = 0; nt < 7; ++nt) {
        int p  = nt * 16 + lm;          // 0..111
        int ph = p / 14;
        spb[nt] = ph * 16 + (p - ph * 14);
    }

    f32x4 acc[2][7];
    #pragma unroll
    for (int i = 0; i < 2; ++i)
        #pragma unroll
        for (int j = 0; j < 7; ++j)
            acc[i][j] = (f32x4){0.f, 0.f, 0.f, 0.f};

    const unsigned short* wsrc = qwt + (size_t)b * 9 * FOUT * CIN;

    for (int t = 0; t < 9; ++t) {
        __syncthreads();   // prior-tap readers done (also covers slab writes at t=0)
        // stage tap-t weights: 8192 ushorts -> s_w[f][72], 16B chunks
        {
            const unsigned short* src = wsrc + t * FOUT * CIN;
            #pragma unroll
            for (int i = 0; i < 4; ++i) {
                int e = i * 256 + tid;            // 0..1023 chunks of 8
                int f = e >> 3, k = (e & 7) << 3;
                *(uint4*)&s_w[f * 72 + k] = *(const uint4*)&src[e * 8];
            }
        }
        __syncthreads();

        const int kh = t / 3, kw = t - (t / 3) * 3;
        #pragma unroll
        for (int cc = 0; cc < 2; ++cc) {
            const int koff = cc * 32 + q * 8;
            bf16x8 af[2], bfr[7];
            #pragma unroll
            for (int mt = 0; mt < 2; ++mt) {
                int f = (wave * 2 + mt) * 16 + lm;        // A row m = lane&15
                af[mt] = *(const bf16x8*)&s_w[f * 72 + koff];
            }
            #pragma unroll
            for (int nt = 0; nt < 7; ++nt) {
                int sp = spb[nt] + kh * 16 + kw;          // B col n = lane&15
                bfr[nt] = *(const bf16x8*)&s_slab[sp * 64 + (koff ^ ((sp & 7) << 3))];
            }
            #pragma unroll
            for (int mt = 0; mt < 2; ++mt)
                #pragma unroll
                for (int nt = 0; nt < 7; ++nt)
                    acc[mt][nt] = __builtin_amdgcn_mfma_f32_16x16x32_bf16(
                        af[mt], bfr[nt], acc[mt][nt], 0, 0, 0);
        }
    }

    // ---- epilogue: D col = lane&15 (pixel), row = q*4+reg (f-local) ----
    #pragma unroll
    for (int mt = 0; mt < 2; ++mt) {
        #pragma unroll
        for (int r = 0; r < 4; ++r) {
            int f = (wave * 2 + mt) * 16 + q * 4 + r;
            float bv = bias[f];
            float* op = out + ((size_t)(n * FOUT + f) * HH_ + h0) * WW_ + w0;
            #pragma unroll
            for (int nt = 0; nt < 7; ++nt) {
                int ph = spb[nt] >> 4, pw = spb[nt] & 15;
                op[ph * WW_ + pw] = acc[mt][nt][r] + bv;
            }
        }
    }
}

extern "C" void kernel_launch(void* const* d_in, const int* in_sizes, int n_in,
                              void* d_out, int out_size, void* d_ws, size_t ws_size,
                              hipStream_t stream) {
    const float* inputs = (const float*)d_in[0];   // [32][64][56][56]
    const float* kernel = (const float*)d_in[1];   // [1][4][576][128]
    const float* bias   = (const float*)d_in[2];   // [128]
    float* out          = (float*)d_out;           // [32][128][56][56]

    const int nelem = SW * 576 * FOUT;             // 294912 weights

    unsigned*       ws_max = (unsigned*)d_ws;
    unsigned short* ws_qwt = (unsigned short*)((char*)d_ws + 64);

    hipMemsetAsync(ws_max, 0, 4, stream);
    absmax_kernel<<<256, 256, 0, stream>>>(kernel, ws_max, nelem);
    quant_t_kernel<<<(nelem + 255) / 256, 256, 0, stream>>>(kernel, ws_max, ws_qwt);

    dim3 grid(NHG, NN, SW);   // (7, 32, 4) = 896 blocks
    conv_mfma<<<grid, 256, 0, stream>>>(inputs, ws_qwt, bias, out);
}

// Round 4
// 135.978 us; speedup vs baseline: 2.4421x; 1.1084x over previous
//
#include <hip/hip_runtime.h>
#include <hip/hip_bf16.h>

#define CIN   64
#define HH_   56
#define WW_   56
#define FOUT  128
#define NN    32
#define SW    4
#define WB    14
#define HG    8
#define NHG   7
#define NW    (SW*9*FOUT*CIN)   // 294912 weights

typedef __attribute__((ext_vector_type(8))) short bf16x8;
typedef __attribute__((ext_vector_type(4))) float f32x4;

__device__ inline unsigned short f2bf(float x) {
    unsigned u = __float_as_uint(x);
    return (unsigned short)((u + 0x7FFFu + ((u >> 16) & 1u)) >> 16);  // RNE
}

// ---------- kernel 1: partial absmax (no atomics -> no memset node) ----------
__global__ void absmax_part(const float* __restrict__ w, float* __restrict__ part) {
    __shared__ float sm[4];
    int tid = threadIdx.x;
    float m = 0.f;
    for (int idx = blockIdx.x * 256 + tid; idx < NW; idx += 64 * 256)
        m = fmaxf(m, fabsf(w[idx]));
    #pragma unroll
    for (int off = 32; off > 0; off >>= 1)
        m = fmaxf(m, __shfl_down(m, off, 64));
    if ((tid & 63) == 0) sm[tid >> 6] = m;
    __syncthreads();
    if (tid == 0)
        part[blockIdx.x] = fmaxf(fmaxf(sm[0], sm[1]), fmaxf(sm[2], sm[3]));
}

// ---------- kernel 2: reduce partials + quant + reorder to [b][t][f][64] ----------
// k-slot pre-swizzled so conv can global_load_lds LINEARLY and ds_read with
// XOR swizzle: content at slot s of row f is channel c = s ^ ((f&7)<<3).
__global__ void quant_t(const float* __restrict__ w, const float* __restrict__ part,
                        unsigned short* __restrict__ qwt) {
    float pm = part[threadIdx.x & 63];
    #pragma unroll
    for (int off = 1; off < 64; off <<= 1)
        pm = fmaxf(pm, __shfl_xor(pm, off, 64));
    float scale = pm / 7.0f;
    int o = blockIdx.x * 256 + threadIdx.x;
    if (o >= NW) return;
    int ks = o & 63;
    int f  = (o >> 6) & 127;
    int bt = o >> 13;              // b*9 + t
    int t  = bt - (bt / 9) * 9;
    int b  = bt / 9;
    int c  = ks ^ ((f & 7) << 3);
    float v = w[((b * CIN + c) * 9 + t) * FOUT + f];   // orig p = c*9 + (kh*3+kw)
    qwt[o] = f2bf(rintf(v / scale) * scale);
}

// ---------- kernel 3: MFMA implicit-GEMM conv ----------
// Block: (hg, n, stripe). D = 128 f x 128 pix-slots (8 rows x 16 cols, col<14 valid).
// 4 waves: wave = (wf, wp): f-tiles 4wf..4wf+3, p-tiles(rows) 4wp..4wp+3.
__global__ __launch_bounds__(256, 3)
void conv_mfma(const float* __restrict__ in,           // [N][C][H][W] f32
               const unsigned short* __restrict__ qwt, // [SW][9][F][64] bf16 pre-swz
               const float* __restrict__ bias,
               float* __restrict__ out) {              // [N][F][H][W] f32
    const int hg = blockIdx.x, n = blockIdx.y, b = blockIdx.z;
    const int h0 = hg * HG, w0 = b * WB;
    const int tid = threadIdx.x;
    const int wave = tid >> 6, lane = tid & 63;
    const int q = lane >> 4, lm = lane & 15;
    const int wf = wave >> 1, wp = wave & 1;

    __shared__ __align__(16) unsigned short s_slab[160 * 64];   // 20 KiB
    __shared__ __align__(16) unsigned short s_w[2][128 * 64];   // 32 KiB dbuf

    // ---- stage input slab: rows h0-1..h0+8, cols w0-1..w0+14, f32->bf16, swizzled ----
    for (int e = tid; e < 160 * 64; e += 256) {
        int col = e & 15, c = (e >> 4) & 63, hh = e >> 10;
        int hi = h0 - 1 + hh, wi = w0 - 1 + col;
        float v = 0.f;
        if (hi >= 0 && hi < HH_ && wi >= 0 && wi < WW_)
            v = in[((n * CIN + c) * HH_ + hi) * WW_ + wi];
        int pix = hh * 16 + col;
        s_slab[pix * 64 + (c ^ ((pix & 7) << 3))] = f2bf(v);
    }

    const unsigned short* wsrc = qwt + (size_t)b * 9 * FOUT * CIN;

    // prologue: stage tap 0 into buf 0 (async DMA, 16B linear chunks)
    #pragma unroll
    for (int i = 0; i < 4; ++i) {
        int off = (i * 256 + tid) * 8;
        __builtin_amdgcn_global_load_lds(
            (const __attribute__((address_space(1))) void*)(wsrc + off),
            (__attribute__((address_space(3))) void*)(&s_w[0][off]), 16, 0, 0);
    }
    __syncthreads();   // slab ds_writes + tap0 DMA drained

    f32x4 acc[4][4];
    #pragma unroll
    for (int i = 0; i < 4; ++i)
        #pragma unroll
        for (int j = 0; j < 4; ++j)
            acc[i][j] = (f32x4){0.f, 0.f, 0.f, 0.f};

    for (int t = 0; t < 9; ++t) {
        // prefetch next tap into the other buffer; lands during this tap's compute
        if (t < 8) {
            const unsigned short* src = wsrc + (size_t)(t + 1) * FOUT * CIN;
            #pragma unroll
            for (int i = 0; i < 4; ++i) {
                int off = (i * 256 + tid) * 8;
                __builtin_amdgcn_global_load_lds(
                    (const __attribute__((address_space(1))) void*)(src + off),
                    (__attribute__((address_space(3))) void*)(&s_w[(t + 1) & 1][off]),
                    16, 0, 0);
            }
        }
        const int kh = t / 3, kw = t - (t / 3) * 3;
        const unsigned short* wb_ = s_w[t & 1];

        #pragma unroll
        for (int cc = 0; cc < 2; ++cc) {
            const int koff = cc * 32 + q * 8;
            bf16x8 af[4], bfr[4];
            #pragma unroll
            for (int m = 0; m < 4; ++m) {
                int f = (wf * 4 + m) * 16 + lm;      // A row = lane&15
                af[m] = *(const bf16x8*)&wb_[f * 64 + (koff ^ ((f & 7) << 3))];
            }
            #pragma unroll
            for (int p = 0; p < 4; ++p) {
                // B col = lane&15 = slab col; wrap keeps garbage lanes in-bounds
                int sp = (wp * 4 + p + kh) * 16 + ((lm + kw) & 15);
                bfr[p] = *(const bf16x8*)&s_slab[sp * 64 + (koff ^ ((sp & 7) << 3))];
            }
            #pragma unroll
            for (int m = 0; m < 4; ++m)
                #pragma unroll
                for (int p = 0; p < 4; ++p)
                    acc[m][p] = __builtin_amdgcn_mfma_f32_16x16x32_bf16(
                        af[m], bfr[p], acc[m][p], 0, 0, 0);
        }
        if (t < 8) __syncthreads();   // drain next-tap DMA + this-tap LDS reads
    }

    // ---- epilogue: D col = lane&15 (pixel col), row = q*4+r (f-local) ----
    #pragma unroll
    for (int m = 0; m < 4; ++m) {
        #pragma unroll
        for (int r = 0; r < 4; ++r) {
            int f = (wf * 4 + m) * 16 + q * 4 + r;
            float bv = bias[f];
            if (lm < WB) {
                #pragma unroll
                for (int p = 0; p < 4; ++p) {
                    int row = wp * 4 + p;
                    out[(((size_t)n * FOUT + f) * HH_ + h0 + row) * WW_ + w0 + lm] =
                        acc[m][p][r] + bv;
                }
            }
        }
    }
}

extern "C" void kernel_launch(void* const* d_in, const int* in_sizes, int n_in,
                              void* d_out, int out_size, void* d_ws, size_t ws_size,
                              hipStream_t stream) {
    const float* inputs = (const float*)d_in[0];   // [32][64][56][56]
    const float* kernel = (const float*)d_in[1];   // [1][4][576][128]
    const float* bias   = (const float*)d_in[2];   // [128]
    float* out          = (float*)d_out;           // [32][128][56][56]

    float*          part = (float*)d_ws;                          // 64 floats
    unsigned short* qwt  = (unsigned short*)((char*)d_ws + 512);  // 576 KiB

    absmax_part<<<64, 256, 0, stream>>>(kernel, part);
    quant_t<<<(NW + 255) / 256, 256, 0, stream>>>(kernel, part, qwt);

    dim3 grid(NHG, NN, SW);   // (7, 32, 4) = 896 blocks
    conv_mfma<<<grid, 256, 0, stream>>>(inputs, qwt, bias, out);
}

// Round 7
// 117.905 us; speedup vs baseline: 2.8164x; 1.1533x over previous
//
#include <hip/hip_runtime.h>
#include <hip/hip_bf16.h>

#define CIN   64
#define HH_   56
#define WW_   56
#define FOUT  128
#define NN    32
#define SW    4
#define WB    14
#define HB    14                     // output rows per block
#define NW    (SW*9*FOUT*CIN)        // 294912 weights
#define QWT_PER_B (8*9*2*64*8)       // 73728 shorts per stripe

typedef __attribute__((ext_vector_type(8))) short bf16x8;
typedef __attribute__((ext_vector_type(4))) float f32x4;

__device__ inline unsigned short f2bf(float x) {
    unsigned u = __float_as_uint(x);
    return (unsigned short)((u + 0x7FFFu + ((u >> 16) & 1u)) >> 16);  // RNE
}

// ---------- kernel 1: partial absmax ----------
__global__ void absmax_part(const float* __restrict__ w, float* __restrict__ part) {
    __shared__ float sm[4];
    int tid = threadIdx.x;
    float m = 0.f;
    for (int idx = blockIdx.x * 256 + tid; idx < NW; idx += 64 * 256)
        m = fmaxf(m, fabsf(w[idx]));
    #pragma unroll
    for (int off = 32; off > 0; off >>= 1)
        m = fmaxf(m, __shfl_down(m, off, 64));
    if ((tid & 63) == 0) sm[tid >> 6] = m;
    __syncthreads();
    if (tid == 0)
        part[blockIdx.x] = fmaxf(fmaxf(sm[0], sm[1]), fmaxf(sm[2], sm[3]));
}

// ---------- kernel 2: quant + pack into MFMA A-fragment order ----------
// layout: qwt[b][ft][t][cc][lane][8]; content = qw[f = ft*16+(lane&15)]
//         [c = cc*32 + (lane>>4)*8 + r] for tap t.  (k within tap = channel)
__global__ void quant_pack(const float* __restrict__ w, const float* __restrict__ part,
                           unsigned short* __restrict__ qwt) {
    float pm = part[threadIdx.x & 63];
    #pragma unroll
    for (int off = 1; off < 64; off <<= 1)
        pm = fmaxf(pm, __shfl_xor(pm, off, 64));
    float scale = pm / 7.0f;
    int o = blockIdx.x * 256 + threadIdx.x;
    if (o >= NW) return;
    int r    = o & 7;
    int lane = (o >> 3) & 63;
    int cc   = (o >> 9) & 1;
    int idx  = o >> 10;            // b*72 + ft*9 + t
    int t    = idx % 9;
    int ft   = (idx / 9) & 7;
    int b    = idx / 72;
    int f = ft * 16 + (lane & 15);
    int c = cc * 32 + (lane >> 4) * 8 + r;
    float v = w[((b * CIN + c) * 9 + t) * FOUT + f];   // orig p = c*9 + t
    qwt[o] = f2bf(rintf(v / scale) * scale);
}

// ---------- kernel 3: conv, weights-in-registers, single barrier ----------
// Block (hgb, n, b): 128 f x 14 rows x 14 cols. 8 waves = (wf 0..3, wp 0..1):
// wave owns f-tiles {2wf,2wf+1} (A-frags in VGPR, all 9 taps) x 7 rows (wp).
__global__ __launch_bounds__(512, 2)
void conv_mfma(const float* __restrict__ in,           // [N][C][H][W] f32
               const unsigned short* __restrict__ qwt, // packed A-fragments
               const float* __restrict__ bias,
               float* __restrict__ out) {              // [N][F][H][W] f32
    const int hgb = blockIdx.x, n = blockIdx.y, b = blockIdx.z;
    const int h0 = hgb * HB, w0 = b * WB;
    const int tid = threadIdx.x;
    const int wave = tid >> 6, lane = tid & 63;
    const int q = lane >> 4, lm = lane & 15;
    const int wf = wave >> 1, wp = wave & 1;

    // slab[pix = row*16+col][c] bf16, swizzle c ^ ((col&7)<<3)  (pix&7 == col&7)
    __shared__ __align__(16) unsigned short s_slab[256 * 64];   // 32 KiB

    // ---- weight A-fragments -> registers: 36 coalesced 16B loads ----
    const unsigned short* wbase = qwt + (size_t)b * QWT_PER_B + lane * 8;
    bf16x8 wt[2][9][2];
    #pragma unroll
    for (int m = 0; m < 2; ++m)
        #pragma unroll
        for (int t = 0; t < 9; ++t)
            #pragma unroll
            for (int cc = 0; cc < 2; ++cc)
                wt[m][t][cc] = *(const bf16x8*)&wbase[((((wf * 2 + m) * 9) + t) * 2 + cc) * 512];

    // ---- stage slab: rows h0-1..h0+14, cols w0-1..w0+14, c-pairs packed b32 ----
    #pragma unroll
    for (int i = 0; i < 16; ++i) {
        int e = i * 512 + tid;
        int cp  = e & 15;               // col 0..15
        int c0  = ((e >> 4) & 31) * 2;  // even channel
        int row = e >> 9;               // 0..15
        int hi = h0 - 1 + row, wi = w0 - 1 + cp;
        float v0 = 0.f, v1 = 0.f;
        if (hi >= 0 && hi < HH_ && wi >= 0 && wi < WW_) {
            const float* p = &in[((n * CIN + c0) * HH_ + hi) * WW_ + wi];
            v0 = p[0]; v1 = p[HH_ * WW_];
        }
        unsigned pk = (unsigned)f2bf(v0) | ((unsigned)f2bf(v1) << 16);
        int pix = row * 16 + cp;
        *(unsigned*)&s_slab[pix * 64 + (c0 ^ ((cp & 7) << 3))] = pk;
    }
    __syncthreads();   // the only barrier

    f32x4 acc[2][7];
    #pragma unroll
    for (int m = 0; m < 2; ++m)
        #pragma unroll
        for (int p = 0; p < 7; ++p)
            acc[m][p] = (f32x4){0.f, 0.f, 0.f, 0.f};

    // ---- K loop: 9 taps x 2 cc, pure ds_read + MFMA ----
    #pragma unroll
    for (int t = 0; t < 9; ++t) {
        const int kh = t / 3, kw = t - (t / 3) * 3;
        const int sc  = (lm + kw) & 15;        // slab col (dead lanes wrap, discarded)
        const int swz = (sc & 7) << 3;
        #pragma unroll
        for (int cc = 0; cc < 2; ++cc) {
            const int koff = cc * 32 + q * 8;
            bf16x8 bfr[7];
            #pragma unroll
            for (int p = 0; p < 7; ++p) {
                int srow = wp * 7 + p + kh;    // 0..15
                bfr[p] = *(const bf16x8*)&s_slab[(srow * 16 + sc) * 64 + (koff ^ swz)];
            }
            #pragma unroll
            for (int m = 0; m < 2; ++m)
                #pragma unroll
                for (int p = 0; p < 7; ++p)
                    acc[m][p] = __builtin_amdgcn_mfma_f32_16x16x32_bf16(
                        wt[m][t][cc], bfr[p], acc[m][p], 0, 0, 0);
        }
    }

    // ---- epilogue: D col = lm (pixel col), row = q*4+r (f-local) ----
    if (lm < WB) {
        #pragma unroll
        for (int m = 0; m < 2; ++m) {
            #pragma unroll
            for (int r = 0; r < 4; ++r) {
                int f = (wf * 2 + m) * 16 + q * 4 + r;
                float bv = bias[f];
                float* op = &out[(((size_t)n * FOUT + f) * HH_ + h0 + wp * 7) * WW_ + w0 + lm];
                #pragma unroll
                for (int p = 0; p < 7; ++p)
                    op[p * WW_] = acc[m][p][r] + bv;
            }
        }
    }
}

extern "C" void kernel_launch(void* const* d_in, const int* in_sizes, int n_in,
                              void* d_out, int out_size, void* d_ws, size_t ws_size,
                              hipStream_t stream) {
    const float* inputs = (const float*)d_in[0];   // [32][64][56][56]
    const float* kernel = (const float*)d_in[1];   // [1][4][576][128]
    const float* bias   = (const float*)d_in[2];   // [128]
    float* out          = (float*)d_out;           // [32][128][56][56]

    float*          part = (float*)d_ws;                          // 64 floats
    unsigned short* qwt  = (unsigned short*)((char*)d_ws + 512);  // 576 KiB packed

    absmax_part<<<64, 256, 0, stream>>>(kernel, part);
    quant_pack<<<(NW + 255) / 256, 256, 0, stream>>>(kernel, part, qwt);

    dim3 grid(HH_ / HB, NN, SW);   // (4, 32, 4) = 512 blocks
    conv_mfma<<<grid, 512, 0, stream>>>(inputs, qwt, bias, out);
}